// Round 13
// baseline (337.364 us; speedup 1.0000x reference)
//
#include <hip/hip_runtime.h>

// Problem constants (fixed by setup_inputs)
#define BB 4
#define Q 75
#define WAY 5
#define HW 100
#define D 640
#define M 500          // shot*HW
#define QROWS 7500     // Q*HW
#define NRF 472        // padded row-frags per b: 59 blocks * 8 (7552 rows)

// ws layout: floats at low offsets, pre-split frag-order arrays after.
// Since r11: single RNE-bf16 product — only BH and AH regions used.
#define WS_FEAT 244800    // BB*Q*10 = 3000 floats (cos slots 0..4, sim slots 5..9)
#define WS_BH_BYTE 1048576u                       // 20*32*20*1024 = 13107200
#define WS_AH_BYTE (14155776u + 13107200u)        // 27262976; 4*472*20*1024 = 38666240

using short8  = __attribute__((ext_vector_type(8))) short;
using short4v = __attribute__((ext_vector_type(4))) short;
using float4v = __attribute__((ext_vector_type(4))) float;

__device__ __forceinline__ unsigned short bf16_rne(float x) {
    unsigned u = __float_as_uint(x);
    return (unsigned short)((u + 0x7fffu + ((u >> 16) & 1u)) >> 16);
}

__device__ __forceinline__ void rne_store4(float4 v, float s, short* dh) {
    short4v hv;
    hv[0] = (short)bf16_rne(v.x * s);
    hv[1] = (short)bf16_rne(v.y * s);
    hv[2] = (short)bf16_rne(v.z * s);
    hv[3] = (short)bf16_rne(v.w * s);
    *(short4v*)dh = hv;
}

// ---------------- kernel 0: MERGED pre-split A+B (RNE bf16, hi only) ----------
// Unchanged from round 12 (passing, control). Block 0 zeroes WS_FEAT.
__global__ __launch_bounds__(256) void presplit_ab(const float* __restrict__ xq,
                                                   const float* __restrict__ xs,
                                                   float* __restrict__ ws) {
    __shared__ __attribute__((aligned(16))) char smem[42560];
    float* partial = (float*)smem;                       // 256 f
    float* invS    = (float*)(smem + 1024);              // 16 f
    char*  stage   = smem + 1088;                        // 16 rows x 2576 B
    short (*Sh)[648] = (short (*)[648])(smem + 1088);    // overlays stage

    int bid = blockIdx.x;
    int tid = threadIdx.x;
    if (bid == 0) {
        for (int i = tid; i < BB * Q * 10; i += 256) ws[WS_FEAT + i] = 0.f;
    }

    bool isB = (bid < 640);
    int bw = 0, b = 0, rf, rowbase, limit;
    const char* srcbase;
    if (isB) {
        bw = bid >> 5; rf = bid & 31;
        rowbase = rf * 16; limit = M;
        srcbase = (const char*)(xs + ((size_t)bw * M + rowbase) * D);
    } else {
        int a = bid - 640;
        b = a / NRF; rf = a % NRF;
        rowbase = rf * 16; limit = QROWS;
        srcbase = (const char*)(xq + ((size_t)b * QROWS + rowbase) * D);
    }

    // phase 1: coalesced stage (predicated against tail-block OOB -> zeros)
    #pragma unroll
    for (int i = 0; i < 10; ++i) {
        int off = i * 4096 + tid * 16;          // byte offset within 40KB block
        int rl  = off / 2560;                   // local row 0..15 (const-div)
        bool ok = (rowbase + rl < limit);
        float4 vv = ok ? *(const float4*)(srcbase + off)
                       : make_float4(0.f, 0.f, 0.f, 0.f);
        *(float4*)(stage + off + rl * 16) = vv; // +16B pad per row
    }
    __syncthreads();

    // phase 2: per-(rho,kc) slice from LDS; ss in the original order
    int rho = tid & 15;
    int kc  = tid >> 4;
    float4 v[10];
    float ss = 0.f;
    #pragma unroll
    for (int i = 0; i < 10; ++i) {
        v[i] = *(const float4*)(stage + rho * 2576 + kc * 160 + i * 16);
        ss += v[i].x*v[i].x + v[i].y*v[i].y + v[i].z*v[i].z + v[i].w*v[i].w;
    }
    partial[tid] = ss;
    __syncthreads();
    if (tid < 16) {
        float sum = 0.f;
        #pragma unroll
        for (int k = 0; k < 16; ++k) sum += partial[k * 16 + tid];
        invS[tid] = (sum > 0.f) ? rsqrtf(sum) : 0.f;
    }
    __syncthreads();

    // phase 3: RNE-bf16 into Sh (overlays stage; all stage reads done)
    float s = invS[rho];
    #pragma unroll
    for (int i = 0; i < 10; ++i) {
        int k = kc * 40 + i * 4;
        rne_store4(v[i], s, &Sh[rho][k]);
    }
    __syncthreads();

    int lane = tid & 63, wvv = tid >> 6;
    int rs = lane & 15, kg = lane >> 4;
    char* wsb = (char*)ws;
    size_t foBase = isB
        ? (size_t)WS_BH_BYTE + (size_t)(bw * 32 + rf) * 20 * 1024
        : (size_t)WS_AH_BYTE + (size_t)(b * NRF + rf) * 20 * 1024;
    #pragma unroll
    for (int p = 0; p < 5; ++p) {
        int kt = wvv * 5 + p;
        short8 hv = *(const short8*)&Sh[rs][kt * 32 + kg * 8];
        *(short8*)(wsb + foBase + (size_t)kt * 1024 + lane * 16) = hv;
    }
}

// ---------------- kernel 4: 64x512 GEMM, B in REGISTERS, A in LDS -------------
// 2360 blocks (118 rt x 20 bw), 512 threads = 8 waves (one 64-col strip each).
// B fragcols are wave-private -> loaded global->reg (frag-order, coalesced,
// L2-resident), compiler-scheduled counted waits, NO barriers for B.
// A (shared by all waves) staged via gl16 by waves 0..3; kt-top WAITV(0)+BAR
// is the drain-then-rendezvous for A only. LDS = 45312 B (A slot + epilogue
// overlay) -> 2 blocks/CU. Numerics identical to r12 (RNE bf16, same chains).
#define NRT2 118
#define NBLK 2360

#define LDS_BYTES 45312
#define MS_OFF 33024u     // top-5 partials: 512*5*4 = 10240 (after Csf 64*129*4)
#define RS_OFF 43264u     // row-sum partials: 512*4 = 2048

#define AS3 __attribute__((address_space(3)))
#define AS1 __attribute__((address_space(1)))

__device__ __forceinline__ void gl16(const void* g, AS3 char* l) {
    __builtin_amdgcn_global_load_lds((const AS1 unsigned int*)g,
                                     (AS3 unsigned int*)l, 16, 0, 0);
}

#define BAR()   __builtin_amdgcn_s_barrier()
#define SB0()   __builtin_amdgcn_sched_barrier(0)
#define WAITV0() asm volatile("s_waitcnt vmcnt(0)")
#define LGKM(n)  asm volatile("s_waitcnt lgkmcnt(" #n ")")

// branchless sorted insert of v into descending (a0..a4)
#define INS5(a0,a1,a2,a3,a4,v) { \
    float n0 = fminf(a0, v); a0 = fmaxf(a0, v); \
    float n1 = fminf(a1, n0); a1 = fmaxf(a1, n0); \
    float n2 = fminf(a2, n1); a2 = fmaxf(a2, n1); \
    float n3 = fminf(a3, n2); a3 = fmaxf(a3, n2); \
    a4 = fmaxf(a4, n3); }

__global__ __launch_bounds__(512, 4) void dn4_kernel(const float* __restrict__ ws_ro,
                                                     float* __restrict__ ws) {
    __shared__ __attribute__((aligned(16))) char lds[LDS_BYTES];
    AS3 char* lp = (AS3 char*)lds;

    // XCD swizzle: 2360 = 8 * 295 (exact)
    int bid = blockIdx.x;
    int wg = (bid & 7) * 295 + (bid >> 3);
    int bw = wg / NRT2;    // 0..19 (contiguous per XCD -> B stays L2-hot)
    int rt = wg % NRT2;    // 0..117
    int wy = bw % WAY, b = bw / WAY;

    int tid  = threadIdx.x;
    int lane = tid & 63;
    int wv   = tid >> 6;          // wave 0..7 = col strip (64 cols each)
    int lq   = lane >> 4, lfree = lane & 15;

    const char* gbase = (const char*)ws_ro;

    // ---- A staging (waves 0..3, one frag each, gl16 -> LDS slot) -----------
    int frA = rt * 4 + (wv & 3);                     // <= 117*4+3 = 471 < NRF
    unsigned aOff  = (unsigned)((b * NRF + frA) * 20) * 1024u + (unsigned)(lane * 16);
    unsigned aDstH = (unsigned)((wv & 3) * 1024);
    #define ISS_A(t2) { if (wv < 4) \
        gl16(gbase + (size_t)(WS_AH_BYTE + aOff + (unsigned)(t2) * 1024u), lp + aDstH); }

    // ---- B addresses (wave-private fragcols, global->reg) ------------------
    unsigned bAddr[4];
    #pragma unroll
    for (int g = 0; g < 4; ++g) {
        unsigned c = (unsigned)((wv >> 1) * 8 + 2 * g + (wv & 1));   // fragcol 0..31
        bAddr[g] = WS_BH_BYTE + (unsigned)((bw * 32 + (int)c) * 20) * 1024u
                 + (unsigned)(lane * 16);
    }
    #define LDB(dst, g, t2) { \
        dst = *(const short8*)(gbase + (size_t)bAddr[g] + (size_t)(t2) * 1024u); }

    // prologue: A(0) staged; bp = cols 0,1 of kt 0
    ISS_A(0);
    short8 bp0, bp1, bq0, bq1;
    LDB(bp0, 0, 0); LDB(bp1, 1, 0);

    float4v acc[4][4];
    #pragma unroll
    for (int jj = 0; jj < 4; ++jj)
        #pragma unroll
        for (int ii = 0; ii < 4; ++ii) {
            acc[jj][ii][0]=0.f; acc[jj][ii][1]=0.f; acc[jj][ii][2]=0.f; acc[jj][ii][3]=0.f;
        }

    unsigned aRd[4];
    #pragma unroll
    for (int jj = 0; jj < 4; ++jj)
        aRd[jj] = (unsigned)(jj * 1024 + lane * 16);

    short8 ah[4];
    #define RD_A() { \
        _Pragma("unroll") \
        for (int jj = 0; jj < 4; ++jj) \
            ah[jj] = *(const AS3 short8*)(lp + aRd[jj]); }

    // 4 MFMAs on one B column
    #define MFMA_COL(ii, BH) { \
        __builtin_amdgcn_s_setprio(1); \
        _Pragma("unroll") \
        for (int jj = 0; jj < 4; ++jj) \
            acc[jj][ii] = __builtin_amdgcn_mfma_f32_16x16x32_bf16(ah[jj], BH, acc[jj][ii], 0,0,0); \
        __builtin_amdgcn_s_setprio(0); }

    #pragma unroll 1
    for (int kt = 0; kt < 20; ++kt) {
        // drain my VMEM queue (covers A(kt) gl16 for waves 0..3 and my bp
        // loads), then rendezvous: A(kt) visible to all waves.
        WAITV0();
        BAR(); SB0();

        RD_A(); SB0();
        LDB(bq0, 2, kt); LDB(bq1, 3, kt);   // cols 2,3 of kt (compiler-waited)
        LGKM(0); SB0();                      // my A ds_reads complete
        BAR(); SB0();                        // all waves' A reads done
        if (kt < 19) { ISS_A(kt + 1); }      // restage A (WAR-safe)
        SB0();

        MFMA_COL(0, bp0);
        MFMA_COL(1, bp1);
        if (kt < 19) { LDB(bp0, 0, kt + 1); LDB(bp1, 1, kt + 1); }
        MFMA_COL(2, bq0);
        MFMA_COL(3, bq1);
    }

    // ---- epilogue: PARALLEL top-5 + per-row full sum, 4 passes of 128 cols ---
    AS3 float* Csf = (AS3 float*)lp;                 // [64][129]
    AS3 float* Ms  = (AS3 float*)(lp + MS_OFF);      // [512][5]
    AS3 float* Rs  = (AS3 float*)(lp + RS_OFF);      // [512]
    float t0=-1e30f,t1=-1e30f,t2=-1e30f,t3=-1e30f,t4=-1e30f;
    float rsum = 0.f;
    int srow = tid & 63;
    int cq   = tid >> 6;          // 0..7: 16-col chunk within the 128-col pass

    #pragma unroll 1
    for (int pass = 0; pass < 4; ++pass) {
        __syncthreads();
        if ((wv >> 1) == pass) {  // strips 2*pass and 2*pass+1 write
            #pragma unroll
            for (int jj = 0; jj < 4; ++jj)
                #pragma unroll
                for (int ii = 0; ii < 4; ++ii) {
                    int row = jj * 16 + lq * 4;
                    int col = (wv & 1) * 64 + ii * 16 + lfree;   // 0..127
                    #pragma unroll
                    for (int rr = 0; rr < 4; ++rr)
                        Csf[(row + rr) * 129 + col] = acc[jj][ii][rr];
                }
        }
        __syncthreads();
        int vlim = M - pass * 128 - (cq << 4);   // valid count in my 16-col chunk
        const AS3 float* rowp = Csf + srow * 129 + (cq << 4);
        #pragma unroll
        for (int c = 0; c < 16; ++c) {
            float vraw = rowp[c];
            bool ok = (c < vlim);
            rsum += ok ? vraw : 0.f;
            float v = ok ? vraw : -1e30f;
            INS5(t0, t1, t2, t3, t4, v);
        }
    }

    __syncthreads();
    {
        AS3 float* mp = Ms + tid * 5;
        mp[0] = t0; mp[1] = t1; mp[2] = t2; mp[3] = t3; mp[4] = t4;
        Rs[tid] = rsum;
    }
    __syncthreads();
    if (tid < 64) {
        float u0=-1e30f,u1=-1e30f,u2=-1e30f,u3=-1e30f,u4=-1e30f;
        float rowsum = 0.f;
        #pragma unroll
        for (int k = 0; k < 8; ++k) {
            const AS3 float* qp = Ms + (tid + (k << 6)) * 5;
            #pragma unroll
            for (int j = 0; j < 5; ++j) {
                float v = qp[j];
                INS5(u0, u1, u2, u3, u4, v);
            }
            rowsum += Rs[tid + (k << 6)];
        }
        int rowg = rt * 64 + tid;
        if (rowg < QROWS) {
            int q = rowg / HW;
            atomicAdd(&ws[WS_FEAT + (b * Q + q) * 10 + 5 + wy],
                      (u0 + u1 + u2 + u3 + u4) * (1.f / M));
            atomicAdd(&ws[WS_FEAT + (b * Q + q) * 10 + wy],
                      rowsum * (1.f / (HW * (float)M)));
        }
    }
}

// ---------------- kernel 5: BatchNorm (training stats over q) + dilated conv ---
__global__ void bn_conv_kernel(const float* __restrict__ gamma, const float* __restrict__ beta,
                               const float* __restrict__ convw, const float* __restrict__ wsr,
                               float* __restrict__ out) {
    __shared__ float f[Q * 10];
    __shared__ float mu[10], rstd[10];
    int b = blockIdx.x;
    const float* feat = wsr + WS_FEAT + b * Q * 10;
    int t = threadIdx.x;
    for (int i = t; i < Q * 10; i += 384) f[i] = feat[i];
    __syncthreads();
    if (t < 10) {
        float s = 0.f;
        for (int q = 0; q < Q; ++q) s += f[q * 10 + t];
        float m = s / Q;
        float ss = 0.f;
        for (int q = 0; q < Q; ++q) { float d = f[q * 10 + t] - m; ss += d * d; }
        mu[t] = m;
        rstd[t] = rsqrtf(ss / Q + 1e-5f);
    }
    __syncthreads();
    if (t < Q * WAY) {
        int q = t / WAY, j = t % WAY;
        float bn0 = (f[q * 10 + j]     - mu[j])     * rstd[j]     * gamma[j]     + beta[j];
        float bn1 = (f[q * 10 + 5 + j] - mu[5 + j]) * rstd[5 + j] * gamma[5 + j] + beta[5 + j];
        out[(b * Q + q) * WAY + j] = convw[0] * bn0 + convw[1] * bn1;
    }
}

extern "C" void kernel_launch(void* const* d_in, const int* in_sizes, int n_in,
                              void* d_out, int out_size, void* d_ws, size_t ws_size,
                              hipStream_t stream) {
    const float* xq    = (const float*)d_in[0];
    const float* xs    = (const float*)d_in[1];
    const float* gamma = (const float*)d_in[2];
    const float* beta  = (const float*)d_in[3];
    const float* convw = (const float*)d_in[4];
    float* ws  = (float*)d_ws;
    float* out = (float*)d_out;

    presplit_ab<<<640 + BB * NRF, 256, 0, stream>>>(xq, xs, ws);
    dn4_kernel<<<NBLK, 512, 0, stream>>>(ws, ws);
    bn_conv_kernel<<<BB, 384, 0, stream>>>(gamma, beta, convw, ws, out);
}

// Round 14
// 307.882 us; speedup vs baseline: 1.0958x; 1.0958x over previous
//
#include <hip/hip_runtime.h>

// Problem constants (fixed by setup_inputs)
#define BB 4
#define Q 75
#define WAY 5
#define HW 100
#define D 640
#define M 500          // shot*HW
#define QROWS 7500     // Q*HW
#define NRF 472        // padded row-frags per b: 59 blocks * 8 (7552 rows)

// ws layout: floats at low offsets, pre-split frag-order arrays after.
// Since r11: single RNE-bf16 product — only BH and AH regions used.
#define WS_FEAT 244800    // BB*Q*10 = 3000 floats (cos slots 0..4, sim slots 5..9)
#define WS_BH_BYTE 1048576u                       // 20*32*20*1024 = 13107200
#define WS_AH_BYTE (14155776u + 13107200u)        // 27262976; 4*472*20*1024 = 38666240

using short8  = __attribute__((ext_vector_type(8))) short;
using short4v = __attribute__((ext_vector_type(4))) short;
using float4v = __attribute__((ext_vector_type(4))) float;

__device__ __forceinline__ unsigned short bf16_rne(float x) {
    unsigned u = __float_as_uint(x);
    return (unsigned short)((u + 0x7fffu + ((u >> 16) & 1u)) >> 16);
}

__device__ __forceinline__ void rne_store4(float4 v, float s, short* dh) {
    short4v hv;
    hv[0] = (short)bf16_rne(v.x * s);
    hv[1] = (short)bf16_rne(v.y * s);
    hv[2] = (short)bf16_rne(v.z * s);
    hv[3] = (short)bf16_rne(v.w * s);
    *(short4v*)dh = hv;
}

// ---------------- kernel 0: pre-split A+B, 8-ROW blocks (7 blocks/CU) ---------
// 5056 blocks of 256 threads; each handles 8 rows (half a 16-row frag).
// bid < 1280: B-mode (bw = bid>>6, group = bid&63); else A-mode (b, group).
// group = rf*2 + half. LDS 21.7KB -> 7 blocks / 28 waves per CU (latency
// hiding across independent block chains). Same arithmetic per element as
// r12's presplit; ss regrouped 32x20 (fp32 reorder ~1e-7, harmless).
#define NB_B 1280
#define NGRP_A 944

__global__ __launch_bounds__(256) void presplit_ab(const float* __restrict__ xq,
                                                   const float* __restrict__ xs,
                                                   float* __restrict__ ws) {
    __shared__ __attribute__((aligned(16))) char smem[21664];
    char*  stage   = smem;                               // 8 rows x 2576 B = 20608
    float* partial = (float*)(smem + 20608);             // 256 f
    float* invS    = (float*)(smem + 21632);             // 8 f
    short (*Sh)[648] = (short (*)[648])smem;             // overlays stage

    int bid = blockIdx.x;
    int tid = threadIdx.x;
    if (bid == 0) {
        for (int i = tid; i < BB * Q * 10; i += 256) ws[WS_FEAT + i] = 0.f;
    }

    bool isB = (bid < NB_B);
    int bw = 0, b = 0, grp, rowbase, limit;
    const char* matbase;
    if (isB) {
        bw = bid >> 6; grp = bid & 63;
        rowbase = grp * 8; limit = M;
        matbase = (const char*)(xs + (size_t)bw * M * D);
    } else {
        int a = bid - NB_B;
        b = a / NGRP_A; grp = a % NGRP_A;
        rowbase = grp * 8; limit = QROWS;
        matbase = (const char*)(xq + (size_t)b * QROWS * D);
    }
    int rf = grp >> 1, half = grp & 1;

    // phase 1: 5 x fully-coalesced 4KB chunk loads (row-clamped, value-zeroed)
    #pragma unroll
    for (int i = 0; i < 5; ++i) {
        int off = i * 4096 + tid * 16;          // 0..20464 within 20KB block
        int rl  = off / 2560;                   // local row 0..7 (const-div)
        int grow = rowbase + rl;
        bool ok = (grow < limit);
        int gclamp = ok ? grow : 0;
        float4 vv = *(const float4*)(matbase + (size_t)gclamp * 2560 + (off - rl * 2560));
        if (!ok) vv = make_float4(0.f, 0.f, 0.f, 0.f);
        *(float4*)(stage + off + rl * 16) = vv; // +16B pad per row (stride 2576)
    }
    __syncthreads();

    // phase 2: thread (rho = tid&7, kc = tid>>3 in 0..31) reads its 20 floats
    int rho = tid & 7;
    int kc  = tid >> 3;
    float4 v[5];
    float ss = 0.f;
    #pragma unroll
    for (int i = 0; i < 5; ++i) {
        v[i] = *(const float4*)(stage + rho * 2576 + kc * 80 + i * 16);
        ss += v[i].x*v[i].x + v[i].y*v[i].y + v[i].z*v[i].z + v[i].w*v[i].w;
    }
    partial[tid] = ss;                           // index = kc*8 + rho
    __syncthreads();
    if (tid < 8) {
        float sum = 0.f;
        #pragma unroll
        for (int k = 0; k < 32; ++k) sum += partial[k * 8 + tid];
        invS[tid] = (sum > 0.f) ? rsqrtf(sum) : 0.f;
    }
    __syncthreads();

    // phase 3: RNE-bf16 into Sh (overlays stage; all stage reads done)
    float s = invS[rho];
    #pragma unroll
    for (int i = 0; i < 5; ++i)
        rne_store4(v[i], s, &Sh[rho][kc * 20 + i * 4]);
    __syncthreads();

    // phase 4: frag-order stores; this block owns rho_full = half*8 + (0..7)
    int lane = tid & 63, wvv = tid >> 6;
    int lrho = lane & 7, lhalf = (lane >> 3) & 1, kg = lane >> 4;
    char* wsb = (char*)ws;
    size_t foBase = isB
        ? (size_t)WS_BH_BYTE + (size_t)(bw * 32 + rf) * 20 * 1024
        : (size_t)WS_AH_BYTE + (size_t)(b * NRF + rf) * 20 * 1024;
    if (lhalf == half) {
        #pragma unroll
        for (int p = 0; p < 5; ++p) {
            int kt = wvv * 5 + p;
            short8 hv = *(const short8*)&Sh[lrho][kt * 32 + kg * 8];
            *(short8*)(wsb + foBase + (size_t)kt * 1024 + lane * 16) = hv;
        }
    }
}

// ---------------- kernel 4: 64x512-tile bf16 GEMM, 2 blocks/CU (r12 EXACT) ----
// 2360 blocks (118 rt x 20 bw), 512 threads = 8 waves, each wave one 64-col
// strip (acc[4][4] = 64 VGPR/thread -> fits 128-VGPR cap WITHOUT spill).
// LDS 69632 B -> 2 blocks/CU; one block's WAITV0 drain overlaps the other's
// MFMAs. R4 sync skeleton. Numerics: RNE bf16 single product.
#define NRT2 118
#define NBLK 2360

#define LDS_BYTES 69632
#define BBASE 4096u       // B dbuf: half h at BBASE + h*32768 (hi only)
#define BHALF 32768u
#define MS_OFF 33024u     // top-5 partials: 512*5*4 = 10240 (overlays staging)
#define RS_OFF 43264u     // row-sum partials: 512*4 = 2048

#define AS3 __attribute__((address_space(3)))
#define AS1 __attribute__((address_space(1)))

__device__ __forceinline__ void gl16(const void* g, AS3 char* l) {
    __builtin_amdgcn_global_load_lds((const AS1 unsigned int*)g,
                                     (AS3 unsigned int*)l, 16, 0, 0);
}

#define BAR()   __builtin_amdgcn_s_barrier()
#define SB0()   __builtin_amdgcn_sched_barrier(0)
#define WAITV0() asm volatile("s_waitcnt vmcnt(0)")
#define LGKM(n)  asm volatile("s_waitcnt lgkmcnt(" #n ")")

// branchless sorted insert of v into descending (a0..a4)
#define INS5(a0,a1,a2,a3,a4,v) { \
    float n0 = fminf(a0, v); a0 = fmaxf(a0, v); \
    float n1 = fminf(a1, n0); a1 = fmaxf(a1, n0); \
    float n2 = fminf(a2, n1); a2 = fmaxf(a2, n1); \
    float n3 = fminf(a3, n2); a3 = fmaxf(a3, n2); \
    a4 = fmaxf(a4, n3); }

__global__ __launch_bounds__(512, 4) void dn4_kernel(const float* __restrict__ ws_ro,
                                                     float* __restrict__ ws) {
    __shared__ __attribute__((aligned(16))) char lds[LDS_BYTES];
    AS3 char* lp = (AS3 char*)lds;

    // XCD swizzle: 2360 = 8 * 295 (exact)
    int bid = blockIdx.x;
    int wg = (bid & 7) * 295 + (bid >> 3);
    int bw = wg / NRT2;    // 0..19 (contiguous per XCD -> B stays L2-hot)
    int rt = wg % NRT2;    // 0..117
    int wy = bw % WAY, b = bw / WAY;

    int tid  = threadIdx.x;
    int lane = tid & 63;
    int wv   = tid >> 6;          // wave 0..7 = col strip (64 cols each)
    int lq   = lane >> 4, lfree = lane & 15;

    const char* gbase = (const char*)ws_ro;

    // ---- staging setup: waves 0..3 stage A frag wv; every wave stages 4 B cols
    int frA = rt * 4 + (wv & 3);                     // <= 117*4+3 = 471 < NRF
    unsigned aOff  = (unsigned)((b * NRF + frA) * 20) * 1024u + (unsigned)(lane * 16);
    unsigned aDstH = (unsigned)((wv & 3) * 1024);
    unsigned bOff[4];
    unsigned bDst[4];
    #pragma unroll
    for (int g = 0; g < 4; ++g) {
        unsigned c = (unsigned)((wv >> 1) * 8 + 2 * g + (wv & 1));   // fragcol 0..31
        bDst[g] = BBASE + c * 1024u;
        bOff[g] = (unsigned)((bw * 32 + (int)c) * 20) * 1024u + (unsigned)(lane * 16);
    }

    #define ISS_A(t2) { if (wv < 4) \
        gl16(gbase + (size_t)(WS_AH_BYTE + aOff + (unsigned)(t2) * 1024u), lp + aDstH); }
    #define ISS_B(g, t2, hwr) { \
        unsigned dd = bDst[g] + (unsigned)(hwr) * BHALF; \
        gl16(gbase + (size_t)(WS_BH_BYTE + bOff[g] + (unsigned)(t2) * 1024u), lp + dd); }

    // prologue: stage tile 0
    ISS_A(0); ISS_B(0, 0, 0); ISS_B(1, 0, 0); ISS_B(2, 0, 0); ISS_B(3, 0, 0);

    float4v acc[4][4];
    #pragma unroll
    for (int jj = 0; jj < 4; ++jj)
        #pragma unroll
        for (int ii = 0; ii < 4; ++ii) {
            acc[jj][ii][0]=0.f; acc[jj][ii][1]=0.f; acc[jj][ii][2]=0.f; acc[jj][ii][3]=0.f;
        }

    unsigned aRd[4];
    #pragma unroll
    for (int jj = 0; jj < 4; ++jj)
        aRd[jj] = (unsigned)(jj * 1024 + lane * 16);
    unsigned bRdBase = (unsigned)(wv * 4 * 1024 + lane * 16);   // my 4 cols

    short8 ah[4];
    short8 bh0, bh1;

    #define RD_A() { \
        _Pragma("unroll") \
        for (int jj = 0; jj < 4; ++jj) \
            ah[jj] = *(const AS3 short8*)(lp + aRd[jj]); }
    #define RD1(BH, ADDR) { BH = *(const AS3 short8*)(lp + (ADDR)); }

    // 4 MFMAs on one B column
    #define MFMA_COL(ii, BH) { \
        __builtin_amdgcn_s_setprio(1); \
        _Pragma("unroll") \
        for (int jj = 0; jj < 4; ++jj) \
            acc[jj][ii] = __builtin_amdgcn_mfma_f32_16x16x32_bf16(ah[jj], BH, acc[jj][ii], 0,0,0); \
        __builtin_amdgcn_s_setprio(0); }

    #pragma unroll 1
    for (int kt = 0; kt < 20; ++kt) {
        int hr = kt & 1;
        unsigned bbB = BBASE + (unsigned)hr * BHALF + bRdBase;

        // validate kt's buffers (per-wave drain; cross-wave via barrier)
        WAITV0();
        BAR(); SB0();

        // read burst: A (4 reads), then my first two B cols (2 reads)
        RD_A(); SB0();
        RD1(bh0, bbB);
        RD1(bh1, bbB + 1024u);
        SB0();
        LGKM(2); SB0();          // A reads complete (last 2 = B c0,c1)

        if (kt < 19) {
            BAR(); SB0();        // all waves' A reads done -> safe to restage
            int t2 = kt + 1, hw2 = hr ^ 1;
            ISS_B(0, t2, hw2); ISS_B(1, t2, hw2); ISS_A(t2);
            ISS_B(2, t2, hw2); ISS_B(3, t2, hw2);
            SB0();
        }

        // 4 column sub-phases; prefetch col ii+2 behind col ii's MFMAs
        MFMA_COL(0, bh0);  RD1(bh0, bbB + 2u * 1024u);
        MFMA_COL(1, bh1);  RD1(bh1, bbB + 3u * 1024u);
        MFMA_COL(2, bh0);
        MFMA_COL(3, bh1);
    }

    // ---- epilogue: PARALLEL top-5 + per-row full sum, 4 passes of 128 cols ---
    AS3 float* Csf = (AS3 float*)lp;                 // [64][129]
    AS3 float* Ms  = (AS3 float*)(lp + MS_OFF);      // [512][5]
    AS3 float* Rs  = (AS3 float*)(lp + RS_OFF);      // [512]
    float t0=-1e30f,t1=-1e30f,t2=-1e30f,t3=-1e30f,t4=-1e30f;
    float rsum = 0.f;
    int srow = tid & 63;
    int cq   = tid >> 6;          // 0..7: 16-col chunk within the 128-col pass

    #pragma unroll 1
    for (int pass = 0; pass < 4; ++pass) {
        __syncthreads();
        if ((wv >> 1) == pass) {  // strips 2*pass and 2*pass+1 write
            #pragma unroll
            for (int jj = 0; jj < 4; ++jj)
                #pragma unroll
                for (int ii = 0; ii < 4; ++ii) {
                    int row = jj * 16 + lq * 4;
                    int col = (wv & 1) * 64 + ii * 16 + lfree;   // 0..127
                    #pragma unroll
                    for (int rr = 0; rr < 4; ++rr)
                        Csf[(row + rr) * 129 + col] = acc[jj][ii][rr];
                }
        }
        __syncthreads();
        int vlim = M - pass * 128 - (cq << 4);   // valid count in my 16-col chunk
        const AS3 float* rowp = Csf + srow * 129 + (cq << 4);
        #pragma unroll
        for (int c = 0; c < 16; ++c) {
            float vraw = rowp[c];
            bool ok = (c < vlim);
            rsum += ok ? vraw : 0.f;
            float v = ok ? vraw : -1e30f;
            INS5(t0, t1, t2, t3, t4, v);
        }
    }

    __syncthreads();
    {
        AS3 float* mp = Ms + tid * 5;
        mp[0] = t0; mp[1] = t1; mp[2] = t2; mp[3] = t3; mp[4] = t4;
        Rs[tid] = rsum;
    }
    __syncthreads();
    if (tid < 64) {
        float u0=-1e30f,u1=-1e30f,u2=-1e30f,u3=-1e30f,u4=-1e30f;
        float rowsum = 0.f;
        #pragma unroll
        for (int k = 0; k < 8; ++k) {
            const AS3 float* qp = Ms + (tid + (k << 6)) * 5;
            #pragma unroll
            for (int j = 0; j < 5; ++j) {
                float v = qp[j];
                INS5(u0, u1, u2, u3, u4, v);
            }
            rowsum += Rs[tid + (k << 6)];
        }
        int rowg = rt * 64 + tid;
        if (rowg < QROWS) {
            int q = rowg / HW;
            atomicAdd(&ws[WS_FEAT + (b * Q + q) * 10 + 5 + wy],
                      (u0 + u1 + u2 + u3 + u4) * (1.f / M));
            atomicAdd(&ws[WS_FEAT + (b * Q + q) * 10 + wy],
                      rowsum * (1.f / (HW * (float)M)));
        }
    }
}

// ---------------- kernel 5: BatchNorm (training stats over q) + dilated conv ---
__global__ void bn_conv_kernel(const float* __restrict__ gamma, const float* __restrict__ beta,
                               const float* __restrict__ convw, const float* __restrict__ wsr,
                               float* __restrict__ out) {
    __shared__ float f[Q * 10];
    __shared__ float mu[10], rstd[10];
    int b = blockIdx.x;
    const float* feat = wsr + WS_FEAT + b * Q * 10;
    int t = threadIdx.x;
    for (int i = t; i < Q * 10; i += 384) f[i] = feat[i];
    __syncthreads();
    if (t < 10) {
        float s = 0.f;
        for (int q = 0; q < Q; ++q) s += f[q * 10 + t];
        float m = s / Q;
        float ss = 0.f;
        for (int q = 0; q < Q; ++q) { float d = f[q * 10 + t] - m; ss += d * d; }
        mu[t] = m;
        rstd[t] = rsqrtf(ss / Q + 1e-5f);
    }
    __syncthreads();
    if (t < Q * WAY) {
        int q = t / WAY, j = t % WAY;
        float bn0 = (f[q * 10 + j]     - mu[j])     * rstd[j]     * gamma[j]     + beta[j];
        float bn1 = (f[q * 10 + 5 + j] - mu[5 + j]) * rstd[5 + j] * gamma[5 + j] + beta[5 + j];
        out[(b * Q + q) * WAY + j] = convw[0] * bn0 + convw[1] * bn1;
    }
}

extern "C" void kernel_launch(void* const* d_in, const int* in_sizes, int n_in,
                              void* d_out, int out_size, void* d_ws, size_t ws_size,
                              hipStream_t stream) {
    const float* xq    = (const float*)d_in[0];
    const float* xs    = (const float*)d_in[1];
    const float* gamma = (const float*)d_in[2];
    const float* beta  = (const float*)d_in[3];
    const float* convw = (const float*)d_in[4];
    float* ws  = (float*)d_ws;
    float* out = (float*)d_out;

    presplit_ab<<<NB_B + BB * NGRP_A, 256, 0, stream>>>(xq, xs, ws);
    dn4_kernel<<<NBLK, 512, 0, stream>>>(ws, ws);
    bn_conv_kernel<<<BB, 384, 0, stream>>>(gamma, beta, convw, ws, out);
}